// Round 7
// baseline (6726.208 us; speedup 1.0000x reference)
//
#include <hip/hip_runtime.h>
#include <math.h>

// TGCN: B=16, T=12, N=1000, H=128, NL=2
#define BB 16
#define TT 12
#define NN 1000
#define HH 128
#define CC 129
#define NROW 16000
#define GR 160            // Gfull rows per b (0:x, 1..128:h^T, 129..159:zero)
#define KP 1024           // k / col dim of Gfull rows
#define CP2 160           // stage-2 K (c padded)
#define SPS 168           // sP stride (bf16)
#define NBLK 256

// LDS map (persistent kernel): [0,131072) sL 64x1024 bf16 in 1KB chunks;
// [131072,152576) region: G dbuf 2x9216 during K-loop, then sP/sGT/sT/sO overlays;
// [152576,155136) sScal 640 f32; [155136,159232) sSt 1024 f32.
#define OFF_REGION 131072
#define OFF_SCAL   152576
#define OFF_SST    155136
#define SMEM_TOTAL 159232

typedef __attribute__((ext_vector_type(4))) float f32x4;
typedef __attribute__((ext_vector_type(8))) __bf16 bf16x8;

#define MFMA16(A, B, C) __builtin_amdgcn_mfma_f32_16x16x32_bf16((A), (B), (C), 0, 0, 0)

__device__ __forceinline__ float sigmoidf_(float x) { return 1.0f / (1.0f + expf(-x)); }

// ---------------- grid barrier (per-phase counter, agent scope) ----------------
__device__ __forceinline__ void gridbar(int* bar, int idx) {
    __syncthreads();
    if (threadIdx.x == 0) {
        __threadfence();
        __hip_atomic_fetch_add(bar + idx, 1, __ATOMIC_ACQ_REL, __HIP_MEMORY_SCOPE_AGENT);
        while (__hip_atomic_load(bar + idx, __ATOMIC_ACQUIRE, __HIP_MEMORY_SCOPE_AGENT) < NBLK)
            __builtin_amdgcn_s_sleep(1);
    }
    __syncthreads();
}

// ---------------- laplacian ----------------
__global__ void k_softmax(const float* __restrict__ adj, float* __restrict__ a) {
    int i = blockIdx.x;
    int t = threadIdx.x;
    __shared__ float red[256];
    float m = -1e30f;
    for (int j = t; j < NN; j += 256) m = fmaxf(m, adj[i * NN + j]);
    red[t] = m; __syncthreads();
    for (int s = 128; s > 0; s >>= 1) { if (t < s) red[t] = fmaxf(red[t], red[t + s]); __syncthreads(); }
    m = red[0]; __syncthreads();
    float sum = 0.f;
    for (int j = t; j < NN; j += 256) sum += expf(adj[i * NN + j] - m);
    red[t] = sum; __syncthreads();
    for (int s = 128; s > 0; s >>= 1) { if (t < s) red[t] += red[t + s]; __syncthreads(); }
    float inv = 1.0f / red[0];
    for (int j = t; j < NN; j += 256) a[i * NN + j] = expf(adj[i * NN + j] - m) * inv;
}

__global__ __launch_bounds__(256) void k_build_Lt(const float* __restrict__ a, __bf16* __restrict__ Lb) {
    __shared__ float s[64][65];
    int bi = blockIdx.x * 64;
    int bj = blockIdx.y * 64;
    int t = threadIdx.x;
    for (int q = t; q < 64 * 64; q += 256) {
        int r = q >> 6, c = q & 63;
        int jj = bj + r, ii = bi + c;
        s[r][c] = (jj < NN && ii < NN) ? a[jj * NN + ii] : 0.f;
    }
    __syncthreads();
    for (int q = t; q < 64 * 64; q += 256) {
        int r = q >> 6, c = q & 63;
        int ii = bi + r, jj = bj + c;
        if (ii < NN && jj < NN)
            Lb[(size_t)ii * KP + jj] = (__bf16)(0.5f * (s[c][r] + (ii == jj ? 1.0f : 0.0f)));
    }
}

// ---------------- one-time weight prep ----------------
__global__ void k_prep(const float* __restrict__ wih, const float* __restrict__ whh,
                       const float* __restrict__ proj_w, const float* __restrict__ ow1,
                       const float* __restrict__ ow2, const float* __restrict__ gc1_w,
                       const float* __restrict__ gc2_w,
                       __bf16* __restrict__ WihB, __bf16* __restrict__ WhhB,
                       __bf16* __restrict__ projB, __bf16* __restrict__ w1B,
                       __bf16* __restrict__ w2B, __bf16* __restrict__ W1t,
                       __bf16* __restrict__ W2t) {
    int idx = blockIdx.x * 256 + threadIdx.x;
    if (idx < 49152) { WihB[idx] = (__bf16)wih[idx]; return; }
    idx -= 49152;
    if (idx < 49152) { WhhB[idx] = (__bf16)whh[idx]; return; }
    idx -= 49152;
    if (idx < 16384) { projB[idx] = (__bf16)proj_w[idx]; return; }
    idx -= 16384;
    if (idx < 32768) { w1B[idx] = (__bf16)ow1[idx]; return; }
    idx -= 32768;
    if (idx < 32768) { w2B[idx] = (__bf16)ow2[idx]; return; }
    idx -= 32768;
    if (idx < 2 * 256 * CP2) {
        int l = idx / (256 * CP2); int r = idx % (256 * CP2); int o = r / CP2, c = r % CP2;
        W1t[idx] = (c < CC) ? (__bf16)gc1_w[((size_t)l * CC + c) * 256 + o] : (__bf16)0.f;
        return;
    }
    idx -= 2 * 256 * CP2;
    if (idx < 2 * 128 * CP2) {
        int l = idx / (128 * CP2); int r = idx % (128 * CP2); int o = r / CP2, c = r % CP2;
        W2t[idx] = (c < CC) ? (__bf16)gc2_w[((size_t)l * CC + c) * 128 + o] : (__bf16)0.f;
    }
}

// Gfull0 row0 = x at t=0
__global__ void k_prep_x(const float* __restrict__ inp, __bf16* __restrict__ G0) {
    int idx = blockIdx.x * 256 + threadIdx.x;
    if (idx >= BB * 1024) return;
    int b = idx >> 10, k = idx & 1023;
    G0[(size_t)b * GR * KP + k] = (k < NN) ? (__bf16)inp[(size_t)b * TT * NN + k] : (__bf16)0.f;
}

// ---------------- fused graph-conv phase (device fn, L persistent in LDS) ----------------
#define GL16(SRC, DSTOFF)                                                            \
    __builtin_amdgcn_global_load_lds(                                                \
        (const __attribute__((address_space(1))) unsigned int*)(SRC),                \
        (__attribute__((address_space(3))) unsigned int*)(smem + (DSTOFF)), 16, 0, 0)

template<int MODE>
__device__ __forceinline__ void gemm_phase(
    char* smem, int b, int m0, int tid,
    const __bf16* __restrict__ Gf,
    const __bf16* __restrict__ Wt, const float* __restrict__ bias,
    __bf16* __restrict__ GB, float* __restrict__ u, float* __restrict__ h,
    const float* __restrict__ x_in, int xstride,
    const float* __restrict__ res_w, const float* __restrict__ res_b,
    const float* __restrict__ ln_g, const float* __restrict__ ln_b,
    float* __restrict__ x_out, __bf16* __restrict__ Gnext,
    __bf16* __restrict__ GhSelf, __bf16* __restrict__ outT, int store_out)
{
    __bf16* sP   = (__bf16*)(smem + OFF_REGION);
    __bf16* sGT  = (__bf16*)(smem + OFF_REGION);
    __bf16* sT   = (__bf16*)(smem + OFF_REGION);
    __bf16* sO   = (__bf16*)(smem + OFF_REGION);
    float*  sScal= (float*)(smem + OFF_SCAL);
    float*  sSt  = (float*)(smem + OFF_SST);

    int wave = tid >> 6, lane = tid & 63;
    int lr = lane & 15, lk = lane >> 4;
    int wm = wave >> 2;          // m-half (32 rows)
    int wcg = wave & 3;          // c-group
    int cgbase = (wcg == 0) ? 0 : (wcg == 1 ? 48 : (wcg == 2 ? 80 : 112));
    int NC = (wcg == 0) ? 3 : 2;
    int rgB = cgbase >> 4;

    if (MODE == 0) {
        if (tid < 256) sScal[tid] = bias[tid];
    } else if (tid < 128) {
        sScal[tid] = bias[tid];
        sScal[128 + tid] = res_w[tid];
        sScal[256 + tid] = res_b[tid];
        sScal[384 + tid] = ln_g[tid];
        sScal[512 + tid] = ln_b[tid];
    }

    size_t srowOff = (size_t)b * GR * KP;

#define STAGE_G(BUF, IT) {                                                              \
    GL16(Gf + srowOff + ((size_t)(wave * 16 + lr)) * KP + (IT) * 32 + lk * 8,           \
         OFF_REGION + (BUF) * 9216 + wave * 1024);                                      \
    if (wave == 0)                                                                      \
        GL16(Gf + srowOff + ((size_t)(128 + lr)) * KP + (IT) * 32 + lk * 8,             \
             OFF_REGION + (BUF) * 9216 + 8 * 1024); }

    f32x4 acc[2][3];
#pragma unroll
    for (int i = 0; i < 2; i++)
#pragma unroll
        for (int j = 0; j < 3; j++) acc[i][j] = (f32x4){0.f, 0.f, 0.f, 0.f};

    STAGE_G(0, 0);
    __syncthreads();                 // drains vmcnt(0)+lgkmcnt: buf0 + sScal ready
    int buf = 0;
    for (int it = 0; it < 32; ++it) {
        if (it < 31) {
            STAGE_G(buf ^ 1, it + 1);
            if (wave == 0) asm volatile("s_waitcnt vmcnt(2)\ns_barrier" ::: "memory");
            else           asm volatile("s_waitcnt vmcnt(1)\ns_barrier" ::: "memory");
        } else {
            asm volatile("s_waitcnt vmcnt(0)\ns_barrier" ::: "memory");
        }
        // fragment reads: chunkbase + lane*16 (conflict-free by construction)
        bf16x8 af0 = *(const bf16x8*)(smem + ((wm * 2 + 0) * 32 + it) * 1024 + lane * 16);
        bf16x8 af1 = *(const bf16x8*)(smem + ((wm * 2 + 1) * 32 + it) * 1024 + lane * 16);
        const char* gb = smem + OFF_REGION + buf * 9216;
        bf16x8 b0 = *(const bf16x8*)(gb + (rgB + 0) * 1024 + lane * 16);
        acc[0][0] = MFMA16(af0, b0, acc[0][0]);
        acc[1][0] = MFMA16(af1, b0, acc[1][0]);
        bf16x8 b1 = *(const bf16x8*)(gb + (rgB + 1) * 1024 + lane * 16);
        acc[0][1] = MFMA16(af0, b1, acc[0][1]);
        acc[1][1] = MFMA16(af1, b1, acc[1][1]);
        if (NC == 3) {
            bf16x8 b2 = *(const bf16x8*)(gb + (rgB + 2) * 1024 + lane * 16);
            acc[0][2] = MFMA16(af0, b2, acc[0][2]);
            acc[1][2] = MFMA16(af1, b2, acc[1][2]);
        }
        asm volatile("s_barrier" ::: "memory");
        buf ^= 1;
    }
#undef STAGE_G

    // P -> sP bf16
#pragma unroll
    for (int mf = 0; mf < 2; mf++)
#pragma unroll
        for (int cf = 0; cf < 3; cf++) {
            if (cf < NC) {
#pragma unroll
                for (int i = 0; i < 4; i++)
                    sP[(wm * 32 + mf * 16 + lk * 4 + i) * SPS + cgbase + cf * 16 + lr] =
                        (__bf16)acc[mf][cf][i];
            }
        }
    for (int q = tid; q < 64 * 16; q += 512) sP[(q >> 4) * SPS + 144 + (q & 15)] = (__bf16)0.f;
    __syncthreads();

    // Stage 2: o split across 8 waves
    constexpr int NOF = (MODE == 0) ? 2 : 1;
    int o0 = wave * NOF * 16;
    f32x4 accs[4][NOF];
#pragma unroll
    for (int i = 0; i < 4; i++)
#pragma unroll
        for (int j = 0; j < NOF; j++) accs[i][j] = (f32x4){0.f, 0.f, 0.f, 0.f};
#pragma unroll
    for (int kk2 = 0; kk2 < CP2; kk2 += 32) {
        bf16x8 pa[4];
#pragma unroll
        for (int mf2 = 0; mf2 < 4; mf2++)
            pa[mf2] = *(const bf16x8*)&sP[(mf2 * 16 + lr) * SPS + kk2 + lk * 8];
#pragma unroll
        for (int of = 0; of < NOF; of++) {
            bf16x8 wb = *(const bf16x8*)&Wt[(size_t)(o0 + of * 16 + lr) * CP2 + kk2 + lk * 8];
#pragma unroll
            for (int mf2 = 0; mf2 < 4; mf2++)
                accs[mf2][of] = MFMA16(pa[mf2], wb, accs[mf2][of]);
        }
    }

    if (MODE == 0) {
        if (tid < 8)
            *(bf16x8*)&GB[srowOff + m0 + tid * 8] = *(const bf16x8*)&Gf[srowOff + m0 + tid * 8];
        bool clean = (m0 + 64 <= 500);
        if (clean) {
            // two m-half passes through sGT [256][40]
            for (int mh = 0; mh < 2; ++mh) {
                __syncthreads();      // sP reads (mh=0) / pass-0 reads (mh=1) done
#pragma unroll
                for (int mf2 = 2 * mh; mf2 < 2 * mh + 2; ++mf2)
#pragma unroll
                    for (int of = 0; of < 2; ++of) {
                        int o = wave * 32 + of * 16 + lr;
                        float bv = sScal[o];
#pragma unroll
                        for (int i = 0; i < 4; i++)
                            sGT[o * 40 + (mf2 - 2 * mh) * 16 + lk * 4 + i] =
                                (__bf16)sigmoidf_(accs[mf2][of][i] + bv);
                    }
                __syncthreads();
                for (int q = tid; q < 128 * 8; q += 512) {
                    int j = q >> 3, cg = q & 7;
                    size_t gidx = srowOff + (size_t)(1 + j) * KP + 2 * m0 + mh * 64 + cg * 8;
                    bf16x8 hv = *(const bf16x8*)&Gf[gidx];
                    bf16x8 rv;
#pragma unroll
                    for (int e = 0; e < 8; e++) {
                        float g = (float)sGT[((e & 1) * 128 + j) * 40 + cg * 4 + (e >> 1)];
                        rv[e] = (__bf16)(g * (float)hv[e]);
                    }
                    *(bf16x8*)&GB[gidx] = rv;
                }
            }
        } else {
#pragma unroll
            for (int mf2 = 0; mf2 < 4; mf2++)
#pragma unroll
                for (int of = 0; of < NOF; of++) {
                    int o = o0 + of * 16 + lr;
                    int j = o & 127, hi = o >> 7;
                    float bv = sScal[o];
#pragma unroll
                    for (int i = 0; i < 4; i++) {
                        int m = m0 + mf2 * 16 + lk * 4 + i;
                        if (m >= NN) continue;
                        float g = sigmoidf_(accs[mf2][of][i] + bv);
                        if (m < 500) {
                            size_t gi = srowOff + (size_t)(1 + j) * KP + 2 * m + hi;
                            GB[gi] = (__bf16)(g * (float)Gf[gi]);
                        } else {
                            u[((size_t)b * NN + 2 * (m - 500) + hi) * HH + j] = g;
                        }
                    }
                }
        }
    } else {
        int j = o0 + lr;   // NOF==1
        float hnv[4][4];
        float s_[4][4], ss_[4][4];
#pragma unroll
        for (int a = 0; a < 4; a++)
#pragma unroll
            for (int i = 0; i < 4; i++) { s_[a][i] = 0.f; ss_[a][i] = 0.f; }
        float b2v = sScal[j], rwv = sScal[128 + j], rbv = sScal[256 + j];
#pragma unroll
        for (int mf2 = 0; mf2 < 4; mf2++) {
#pragma unroll
            for (int i = 0; i < 4; i++) {
                int m = m0 + mf2 * 16 + lk * 4 + i;
                int msafe = (m < NN) ? m : (NN - 1);
                size_t ri = ((size_t)b * NN + msafe) * HH + j;
                float cv = tanhf(accs[mf2][0][i] + b2v);
                float uu = u[ri];
                float hv = h[ri];
                float hn = uu * hv + (1.f - uu) * cv;
                if (m < NN) h[ri] = hn;
                hnv[mf2][i] = hn;
                float xv = (m < NN) ? x_in[(size_t)b * xstride + m] : 0.f;
                float y = hn + xv * rwv + rbv;
                accs[mf2][0][i] = y;
                s_[mf2][i] += y; ss_[mf2][i] += y * y;
            }
        }
#pragma unroll
        for (int msk = 1; msk < 16; msk <<= 1)
#pragma unroll
            for (int a = 0; a < 4; a++)
#pragma unroll
                for (int i = 0; i < 4; i++) {
                    s_[a][i] += __shfl_xor(s_[a][i], msk);
                    ss_[a][i] += __shfl_xor(ss_[a][i], msk);
                }
        if (lr == 0) {
#pragma unroll
            for (int a = 0; a < 4; a++)
#pragma unroll
                for (int i = 0; i < 4; i++) {
                    int ml = a * 16 + lk * 4 + i;
                    sSt[wave * 64 + ml] = s_[a][i];
                    sSt[512 + wave * 64 + ml] = ss_[a][i];
                }
        }
        __syncthreads();
        float mu_[4][4], rs_[4][4];
#pragma unroll
        for (int a = 0; a < 4; a++)
#pragma unroll
            for (int i = 0; i < 4; i++) {
                int ml = a * 16 + lk * 4 + i;
                float S = 0.f, SS = 0.f;
#pragma unroll
                for (int w = 0; w < 8; w++) { S += sSt[w * 64 + ml]; SS += sSt[512 + w * 64 + ml]; }
                float mu = S * (1.f / 128.f);
                float var = SS * (1.f / 128.f) - mu * mu;
                mu_[a][i] = mu;
                rs_[a][i] = rsqrtf(var + 1e-5f);
            }
        float xs_[4][4];
        float lg = sScal[384 + j], lb2 = sScal[512 + j];
#pragma unroll
        for (int mf2 = 0; mf2 < 4; mf2++)
#pragma unroll
            for (int i = 0; i < 4; i++) {
                float ov = (accs[mf2][0][i] - mu_[mf2][i]) * rs_[mf2][i] * lg + lb2;
                accs[mf2][0][i] = ov;
                xs_[mf2][i] = ov;
            }
#pragma unroll
        for (int msk = 1; msk < 16; msk <<= 1)
#pragma unroll
            for (int a = 0; a < 4; a++)
#pragma unroll
                for (int i = 0; i < 4; i++) xs_[a][i] += __shfl_xor(xs_[a][i], msk);
        __syncthreads();
        if (lr == 0) {
#pragma unroll
            for (int a = 0; a < 4; a++)
#pragma unroll
                for (int i = 0; i < 4; i++)
                    sSt[wave * 64 + a * 16 + lk * 4 + i] = xs_[a][i];
        }
        __syncthreads();
        if (wave == 0 && lr == 0) {
#pragma unroll
            for (int a = 0; a < 4; a++)
#pragma unroll
                for (int i = 0; i < 4; i++) {
                    int ml = a * 16 + lk * 4 + i;
                    int m = m0 + ml;
                    if (m < NN) {
                        float S = 0.f;
#pragma unroll
                        for (int w = 0; w < 8; w++) S += sSt[w * 64 + ml];
                        float xv = S * (1.f / 128.f);
                        if (x_out) x_out[(size_t)b * NN + m] = xv;
                        if (Gnext) Gnext[(size_t)b * GR * KP + m] = (__bf16)xv;
                    }
                }
        }
        // hn -> GhSelf via sT
#pragma unroll
        for (int mf2 = 0; mf2 < 4; mf2++)
#pragma unroll
            for (int i = 0; i < 4; i++)
                sT[j * 72 + mf2 * 16 + lk * 4 + i] = (__bf16)hnv[mf2][i];
        __syncthreads();
        for (int q = tid; q < 128 * 8; q += 512) {
            int jj = q >> 3, mc = (q & 7) * 8;
            if (m0 + mc < NN)
                *(bf16x8*)&GhSelf[srowOff + (size_t)(1 + jj) * KP + m0 + mc] =
                    *(const bf16x8*)&sT[jj * 72 + mc];
        }
        if (store_out) {
            __syncthreads();
#pragma unroll
            for (int mf2 = 0; mf2 < 4; mf2++)
#pragma unroll
                for (int i = 0; i < 4; i++)
                    sO[(mf2 * 16 + lk * 4 + i) * 136 + j] = (__bf16)accs[mf2][0][i];
            __syncthreads();
            for (int q = tid; q < 64 * 16; q += 512) {
                int ml = q >> 4, jc = (q & 15) * 8;
                int m = m0 + ml;
                if (m < NN)
                    *(bf16x8*)&outT[((size_t)b * NN + m) * HH + jc] = *(const bf16x8*)&sO[ml * 136 + jc];
            }
        }
    }
}

// ---------------- GRU phase (device fn, 64 rows/block, blocks 0..249) ----------------
__device__ __forceinline__ void gru_phase(
    int wg, int tid, float* sScal,
    const __bf16* __restrict__ Xb, float* __restrict__ hg, __bf16* __restrict__ Hb,
    const __bf16* __restrict__ WihB, const __bf16* __restrict__ WhhB,
    const float* __restrict__ bih, const float* __restrict__ bhh,
    const float* __restrict__ inp, __bf16* __restrict__ G0, int tnext)
{
    if (wg >= 250) return;
    int wave = tid >> 6, lane = tid & 63;
    int lr = lane & 15, lk = lane >> 4;
    int wm = wave & 3, wo = wave >> 2;
    int r0 = wg * 64 + wm * 16;
    if (tid < 128) {
        sScal[tid] = bih[tid] + bhh[tid];
        sScal[128 + tid] = bih[128 + tid] + bhh[128 + tid];
        sScal[256 + tid] = bih[256 + tid];
        sScal[384 + tid] = bhh[256 + tid];
    }
    __syncthreads();

    f32x4 rz[8], ni[4], nh[4];
#pragma unroll
    for (int i = 0; i < 8; i++) rz[i] = (f32x4){0.f, 0.f, 0.f, 0.f};
#pragma unroll
    for (int i = 0; i < 4; i++) { ni[i] = (f32x4){0.f, 0.f, 0.f, 0.f}; nh[i] = (f32x4){0.f, 0.f, 0.f, 0.f}; }

    int arow = r0 + lr;
#pragma unroll
    for (int kk = 0; kk < 128; kk += 32) {
        bf16x8 xa = *(const bf16x8*)&Xb[(size_t)arow * HH + kk + lk * 8];
        bf16x8 ha = *(const bf16x8*)&Hb[(size_t)arow * HH + kk + lk * 8];
#pragma unroll
        for (int q = 0; q < 4; q++) {
            int orr = wo * 64 + q * 16 + lr;
            bf16x8 w0 = *(const bf16x8*)&WihB[(size_t)orr * HH + kk + lk * 8];
            rz[q] = MFMA16(xa, w0, rz[q]);
            bf16x8 w1 = *(const bf16x8*)&WhhB[(size_t)orr * HH + kk + lk * 8];
            rz[q] = MFMA16(ha, w1, rz[q]);
            bf16x8 w2 = *(const bf16x8*)&WihB[(size_t)(128 + orr) * HH + kk + lk * 8];
            rz[4 + q] = MFMA16(xa, w2, rz[4 + q]);
            bf16x8 w3 = *(const bf16x8*)&WhhB[(size_t)(128 + orr) * HH + kk + lk * 8];
            rz[4 + q] = MFMA16(ha, w3, rz[4 + q]);
            bf16x8 w4 = *(const bf16x8*)&WihB[(size_t)(256 + orr) * HH + kk + lk * 8];
            ni[q] = MFMA16(xa, w4, ni[q]);
            bf16x8 w5 = *(const bf16x8*)&WhhB[(size_t)(256 + orr) * HH + kk + lk * 8];
            nh[q] = MFMA16(ha, w5, nh[q]);
        }
    }
#pragma unroll
    for (int q = 0; q < 4; q++) {
        int j = wo * 64 + q * 16 + lr;
        float br = sScal[j], bz = sScal[128 + j], bni = sScal[256 + j], bnh = sScal[384 + j];
#pragma unroll
        for (int i = 0; i < 4; i++) {
            int row = r0 + lk * 4 + i;
            float rg = sigmoidf_(rz[q][i] + br);
            float zg = sigmoidf_(rz[4 + q][i] + bz);
            float hv = hg[(size_t)row * HH + j];
            float ng = tanhf(ni[q][i] + bni + rg * (nh[q][i] + bnh));
            float hp = (1.f - zg) * ng + zg * hv;
            hg[(size_t)row * HH + j] = hp;
            Hb[(size_t)row * HH + j] = (__bf16)hp;
        }
    }
    if (wo == 0 && lr == 0 && tnext < TT) {
#pragma unroll
        for (int i = 0; i < 4; i++) {
            int row = r0 + lk * 4 + i;
            int bb = row / NN, n = row - bb * NN;
            G0[(size_t)bb * GR * KP + n] = (__bf16)inp[(size_t)bb * TT * NN + tnext * NN + n];
        }
    }
}

// ---------------- persistent kernel: whole recurrent chain ----------------
__global__ __launch_bounds__(512, 1) void k_persist(
    const __bf16* __restrict__ Lb,
    __bf16* __restrict__ Gfull0, __bf16* __restrict__ Gfull1, __bf16* __restrict__ GfullB,
    const __bf16* __restrict__ W1t, const __bf16* __restrict__ W2t,
    const float* __restrict__ gc1_b, const float* __restrict__ gc2_b,
    float* __restrict__ u, float* __restrict__ h0, float* __restrict__ h1,
    const float* __restrict__ inp, float* __restrict__ xB,
    const float* __restrict__ res_w, const float* __restrict__ res_b,
    const float* __restrict__ ln_g, const float* __restrict__ ln_b,
    float* __restrict__ hg, __bf16* __restrict__ Hb, __bf16* __restrict__ outT,
    const __bf16* __restrict__ WihB, const __bf16* __restrict__ WhhB,
    const float* __restrict__ bih, const float* __restrict__ bhh,
    int* __restrict__ bar)
{
    __shared__ __align__(16) char smem[SMEM_TOTAL];
    int tid = threadIdx.x;
    int wg = blockIdx.x;
    int b = wg & 15;
    int m0 = (wg >> 4) * 64;
    float* sScal = (float*)(smem + OFF_SCAL);

    // prologue: persistent L tile -> sL (chunk layout: ((rg2*32+kstep)*64 + ks*16 + r)*16B)
    for (int p = 0; p < 16; ++p) {
        int q = tid + p * 512;
        int rfull = q >> 7, ksg = q & 127;
        bf16x8 v = *(const bf16x8*)&Lb[(size_t)(m0 + rfull) * KP + ksg * 8];
        int rg2 = rfull >> 4, r = rfull & 15, kstep = ksg >> 2, ks = ksg & 3;
        *(bf16x8*)(smem + ((rg2 * 32 + kstep) * 64 + ks * 16 + r) * 16) = v;
    }
    __syncthreads();

    int bi = 0;
    for (int t = 0; t < TT; ++t) {
        const float* xs0 = inp + (size_t)t * NN;
        // layer 0
        gemm_phase<0>(smem, b, m0, tid, Gfull0, W1t, gc1_b, GfullB, u,
                      nullptr, nullptr, 0, nullptr, nullptr, nullptr, nullptr,
                      nullptr, nullptr, nullptr, nullptr, 0);
        gridbar(bar, bi++);
        gemm_phase<1>(smem, b, m0, tid, GfullB, W2t, gc2_b, nullptr, u, h0,
                      xs0, TT * NN, res_w, res_b, ln_g, ln_b,
                      xB, Gfull1, Gfull0, nullptr, 0);
        gridbar(bar, bi++);
        // layer 1
        gemm_phase<0>(smem, b, m0, tid, Gfull1, W1t + 256 * CP2, gc1_b + 256, GfullB, u,
                      nullptr, nullptr, 0, nullptr, nullptr, nullptr, nullptr,
                      nullptr, nullptr, nullptr, nullptr, 0);
        gridbar(bar, bi++);
        gemm_phase<1>(smem, b, m0, tid, GfullB, W2t + 128 * CP2, gc2_b + 128, nullptr, u, h1,
                      xB, NN, res_w, res_b, ln_g + 128, ln_b + 128,
                      nullptr, nullptr, Gfull1, outT, 1);
        gridbar(bar, bi++);
        // GRU tail step
        gru_phase(wg, tid, sScal, outT, hg, Hb, WihB, WhhB, bih, bhh, inp, Gfull0, t + 1);
        gridbar(bar, bi++);
    }
}

// ---------------- head: proj -> relu MLP -> out, MFMA ----------------
__global__ __launch_bounds__(256) void k_head_mfma(const __bf16* __restrict__ Hb,
                                                   const __bf16* __restrict__ projB,
                                                   const float* __restrict__ pb,
                                                   const __bf16* __restrict__ w1B,
                                                   const float* __restrict__ b1,
                                                   const __bf16* __restrict__ w2B,
                                                   const float* __restrict__ b2,
                                                   float* __restrict__ out) {
    __shared__ __align__(16) __bf16 sH1[64 * 136];
    __shared__ __align__(16) __bf16 sH2[64 * 264];
    int tid = threadIdx.x;
    int r0 = blockIdx.x * 64;
    int wv = tid >> 6, lane = tid & 63;
    int lr = lane & 15, lk = lane >> 4;
    int arow = r0 + wv * 16 + lr;

    f32x4 a1[8];
#pragma unroll
    for (int i = 0; i < 8; i++) a1[i] = (f32x4){0.f, 0.f, 0.f, 0.f};
#pragma unroll
    for (int kk = 0; kk < 128; kk += 32) {
        bf16x8 xa = *(const bf16x8*)&Hb[(size_t)arow * HH + kk + lk * 8];
#pragma unroll
        for (int f = 0; f < 8; f++) {
            bf16x8 wb = *(const bf16x8*)&projB[(size_t)(f * 16 + lr) * HH + kk + lk * 8];
            a1[f] = MFMA16(xa, wb, a1[f]);
        }
    }
#pragma unroll
    for (int f = 0; f < 8; f++) {
        int j = f * 16 + lr;
        float bv = pb[j];
#pragma unroll
        for (int i = 0; i < 4; i++)
            sH1[(wv * 16 + lk * 4 + i) * 136 + j] = (__bf16)(a1[f][i] + bv);
    }
    __syncthreads();

    f32x4 a2[16];
#pragma unroll
    for (int i = 0; i < 16; i++) a2[i] = (f32x4){0.f, 0.f, 0.f, 0.f};
#pragma unroll
    for (int kk = 0; kk < 128; kk += 32) {
        bf16x8 pa = *(const bf16x8*)&sH1[(wv * 16 + lr) * 136 + kk + lk * 8];
#pragma unroll
        for (int f = 0; f < 16; f++) {
            bf16x8 wb = *(const bf16x8*)&w1B[(size_t)(f * 16 + lr) * HH + kk + lk * 8];
            a2[f] = MFMA16(pa, wb, a2[f]);
        }
    }
    __syncthreads();
#pragma unroll
    for (int f = 0; f < 16; f++) {
        int o = f * 16 + lr;
        float bv = b1[o];
#pragma unroll
        for (int i = 0; i < 4; i++)
            sH2[(wv * 16 + lk * 4 + i) * 264 + o] = (__bf16)fmaxf(a2[f][i] + bv, 0.f);
    }
    __syncthreads();

    f32x4 a3[8];
#pragma unroll
    for (int i = 0; i < 8; i++) a3[i] = (f32x4){0.f, 0.f, 0.f, 0.f};
#pragma unroll
    for (int kk = 0; kk < 256; kk += 32) {
        bf16x8 pa = *(const bf16x8*)&sH2[(wv * 16 + lr) * 264 + kk + lk * 8];
#pragma unroll
        for (int f = 0; f < 8; f++) {
            bf16x8 wb = *(const bf16x8*)&w2B[(size_t)(f * 16 + lr) * 256 + kk + lk * 8];
            a3[f] = MFMA16(pa, wb, a3[f]);
        }
    }
#pragma unroll
    for (int f = 0; f < 8; f++) {
        int j = f * 16 + lr;
        float bv = b2[j];
#pragma unroll
        for (int i = 0; i < 4; i++)
            out[(size_t)(r0 + wv * 16 + lk * 4 + i) * HH + j] = a3[f][i] + bv;
    }
}

extern "C" void kernel_launch(void* const* d_in, const int* in_sizes, int n_in,
                              void* d_out, int out_size, void* d_ws, size_t ws_size,
                              hipStream_t stream) {
    const float* inp    = (const float*)d_in[0];
    const float* adj    = (const float*)d_in[1];
    const float* gc1_w  = (const float*)d_in[2];
    const float* gc1_b  = (const float*)d_in[3];
    const float* gc2_w  = (const float*)d_in[4];
    const float* gc2_b  = (const float*)d_in[5];
    const float* ln_g   = (const float*)d_in[6];
    const float* ln_b   = (const float*)d_in[7];
    const float* res_w  = (const float*)d_in[8];
    const float* res_b  = (const float*)d_in[9];
    const float* wih    = (const float*)d_in[10];
    const float* whh    = (const float*)d_in[11];
    const float* bih    = (const float*)d_in[12];
    const float* bhh    = (const float*)d_in[13];
    const float* proj_w = (const float*)d_in[14];
    const float* proj_b = (const float*)d_in[15];
    const float* ow1    = (const float*)d_in[16];
    const float* ob1    = (const float*)d_in[17];
    const float* ow2    = (const float*)d_in[18];
    const float* ob2    = (const float*)d_in[19];
    float* out = (float*)d_out;

    char* ws = (char*)d_ws;
    size_t off = 0;
    __bf16* Lb     = (__bf16*)(ws + off); off += (size_t)KP * KP * 2;          // 2 MB
    __bf16* Gfull0 = (__bf16*)(ws + off); off += (size_t)BB * GR * KP * 2;     // 5 MB
    __bf16* Gfull1 = (__bf16*)(ws + off); off += (size_t)BB * GR * KP * 2;
    __bf16* GfullB = (__bf16*)(ws + off); off += (size_t)BB * GR * KP * 2;
    size_t zgrp1 = off;
    float* h0   = (float*)(ws + off);  off += (size_t)NROW * HH * 4;
    float* h1   = (float*)(ws + off);  off += (size_t)NROW * HH * 4;
    float* hg   = (float*)(ws + off);  off += (size_t)NROW * HH * 4;
    __bf16* Hb  = (__bf16*)(ws + off); off += (size_t)NROW * HH * 2;
    float* u    = (float*)(ws + off);  off += (size_t)NROW * HH * 4;
    __bf16* outT= (__bf16*)(ws + off); off += (size_t)NROW * HH * 2;
    float* xB   = (float*)(ws + off);  off += NROW * 4;
    __bf16* W1t = (__bf16*)(ws + off); off += (size_t)2 * 256 * CP2 * 2;
    __bf16* W2t = (__bf16*)(ws + off); off += (size_t)2 * 128 * CP2 * 2;
    __bf16* WihB= (__bf16*)(ws + off); off += 49152 * 2;
    __bf16* WhhB= (__bf16*)(ws + off); off += 49152 * 2;
    __bf16* projB=(__bf16*)(ws + off); off += 16384 * 2;
    __bf16* w1B = (__bf16*)(ws + off); off += 32768 * 2;
    __bf16* w2B = (__bf16*)(ws + off); off += 32768 * 2;
    int* bar    = (int*)(ws + off);    off += 64 * sizeof(int);
    float* a_sm = u;   // overlay: softmax scratch only used before u's first write

    hipMemsetAsync(bar, 0, 64 * sizeof(int), stream);
    hipMemsetAsync(Lb, 0, zgrp1, stream);                     // Lb + Gfull0/1/B
    hipMemsetAsync(h0, 0, (size_t)NROW * HH * 8, stream);     // h0, h1
    hipMemsetAsync(hg, 0, (size_t)NROW * HH * 6, stream);     // hg, Hb

    k_softmax<<<NN, 256, 0, stream>>>(adj, a_sm);
    k_build_Lt<<<dim3(16, 16), 256, 0, stream>>>(a_sm, Lb);
    k_prep<<<1184, 256, 0, stream>>>(wih, whh, proj_w, ow1, ow2, gc1_w, gc2_w,
                                     WihB, WhhB, projB, w1B, w2B, W1t, W2t);
    k_prep_x<<<64, 256, 0, stream>>>(inp, Gfull0);

    k_persist<<<NBLK, 512, 0, stream>>>(Lb, Gfull0, Gfull1, GfullB, W1t, W2t,
                                        gc1_b, gc2_b, u, h0, h1, inp, xB,
                                        res_w, res_b, ln_g, ln_b,
                                        hg, Hb, outT, WihB, WhhB, bih, bhh, bar);

    k_head_mfma<<<250, 256, 0, stream>>>(Hb, projB, proj_b, w1B, ob1, w2B, ob2, out);
}

// Round 8
// 1444.065 us; speedup vs baseline: 4.6578x; 4.6578x over previous
//
#include <hip/hip_runtime.h>
#include <math.h>

// TGCN: B=16, T=12, N=1000, H=128, NL=2
#define BB 16
#define TT 12
#define NN 1000
#define HH 128
#define CC 129
#define NROW 16000
#define GR 160            // Gfull rows per b (0:x, 1..128:h^T, 129..159:zero)
#define KP 1024
#define CP2 160           // stage-2 K (c padded)
#define SPS 168           // sP stride (bf16)

// LDS map: 3 staging buffers of 26KB (26 chunks x 1KB: 8 L + 18 G), then sP, sScal, sSt.
// Epilogue overlays sGT/sT/sO onto the (dead) staging region.
#define BUFSZ 26624
#define OFF_SP   79872
#define OFF_SCAL 101376
#define OFF_SST  103936
#define SMEMB    108032
#define OFF_SO   20480

typedef __attribute__((ext_vector_type(4))) float f32x4;
typedef __attribute__((ext_vector_type(8))) __bf16 bf16x8;

#define MFMA16(A, B, C) __builtin_amdgcn_mfma_f32_16x16x32_bf16((A), (B), (C), 0, 0, 0)

__device__ __forceinline__ float sigmoidf_(float x) { return 1.0f / (1.0f + expf(-x)); }

// ---------------- laplacian ----------------
__global__ void k_softmax(const float* __restrict__ adj, float* __restrict__ a) {
    int i = blockIdx.x;
    int t = threadIdx.x;
    __shared__ float red[256];
    float m = -1e30f;
    for (int j = t; j < NN; j += 256) m = fmaxf(m, adj[i * NN + j]);
    red[t] = m; __syncthreads();
    for (int s = 128; s > 0; s >>= 1) { if (t < s) red[t] = fmaxf(red[t], red[t + s]); __syncthreads(); }
    m = red[0]; __syncthreads();
    float sum = 0.f;
    for (int j = t; j < NN; j += 256) sum += expf(adj[i * NN + j] - m);
    red[t] = sum; __syncthreads();
    for (int s = 128; s > 0; s >>= 1) { if (t < s) red[t] += red[t + s]; __syncthreads(); }
    float inv = 1.0f / red[0];
    for (int j = t; j < NN; j += 256) a[i * NN + j] = expf(adj[i * NN + j] - m) * inv;
}

__global__ __launch_bounds__(256) void k_build_Lt(const float* __restrict__ a, __bf16* __restrict__ Lb) {
    __shared__ float s[64][65];
    int bi = blockIdx.x * 64;
    int bj = blockIdx.y * 64;
    int t = threadIdx.x;
    for (int q = t; q < 64 * 64; q += 256) {
        int r = q >> 6, c = q & 63;
        int jj = bj + r, ii = bi + c;
        s[r][c] = (jj < NN && ii < NN) ? a[jj * NN + ii] : 0.f;
    }
    __syncthreads();
    for (int q = t; q < 64 * 64; q += 256) {
        int r = q >> 6, c = q & 63;
        int ii = bi + r, jj = bj + c;
        if (ii < NN && jj < NN)
            Lb[(size_t)ii * KP + jj] = (__bf16)(0.5f * (s[c][r] + (ii == jj ? 1.0f : 0.0f)));
    }
}

// ---------------- one-time weight prep ----------------
__global__ void k_prep(const float* __restrict__ wih, const float* __restrict__ whh,
                       const float* __restrict__ proj_w, const float* __restrict__ ow1,
                       const float* __restrict__ ow2, const float* __restrict__ gc1_w,
                       const float* __restrict__ gc2_w,
                       __bf16* __restrict__ WihB, __bf16* __restrict__ WhhB,
                       __bf16* __restrict__ projB, __bf16* __restrict__ w1B,
                       __bf16* __restrict__ w2B, __bf16* __restrict__ W1t,
                       __bf16* __restrict__ W2t) {
    int idx = blockIdx.x * 256 + threadIdx.x;
    if (idx < 49152) { WihB[idx] = (__bf16)wih[idx]; return; }
    idx -= 49152;
    if (idx < 49152) { WhhB[idx] = (__bf16)whh[idx]; return; }
    idx -= 49152;
    if (idx < 16384) { projB[idx] = (__bf16)proj_w[idx]; return; }
    idx -= 16384;
    if (idx < 32768) { w1B[idx] = (__bf16)ow1[idx]; return; }
    idx -= 32768;
    if (idx < 32768) { w2B[idx] = (__bf16)ow2[idx]; return; }
    idx -= 32768;
    if (idx < 2 * 256 * CP2) {
        int l = idx / (256 * CP2); int r = idx % (256 * CP2); int o = r / CP2, c = r % CP2;
        W1t[idx] = (c < CC) ? (__bf16)gc1_w[((size_t)l * CC + c) * 256 + o] : (__bf16)0.f;
        return;
    }
    idx -= 2 * 256 * CP2;
    if (idx < 2 * 128 * CP2) {
        int l = idx / (128 * CP2); int r = idx % (128 * CP2); int o = r / CP2, c = r % CP2;
        W2t[idx] = (c < CC) ? (__bf16)gc2_w[((size_t)l * CC + c) * 128 + o] : (__bf16)0.f;
    }
}

// Gfull0 row0 = x at t=0
__global__ void k_prep_x(const float* __restrict__ inp, __bf16* __restrict__ G0) {
    int idx = blockIdx.x * 256 + threadIdx.x;
    if (idx >= BB * 1024) return;
    int b = idx >> 10, k = idx & 1023;
    G0[(size_t)b * GR * KP + k] = (k < NN) ? (__bf16)inp[(size_t)b * TT * NN + k] : (__bf16)0.f;
}

// ---------------- fused graph-conv + weight matmul + epilogue (+ GRU when STORE) -------
// 1024 threads = 16 waves. Stage-1: all 16 waves (wm = m-half, wcg = 8 c-groups {2,1x7}).
// K=1024 in 16 steps of 64; 3-buffer pipeline, counted vmcnt, XOR-swizzled chunks.
// Stage-2 + epilogue: waves 0-7 (round-6 verified code); waves 8-15 idle through barriers.
#define GL16(SRC, DSTOFF)                                                            \
    __builtin_amdgcn_global_load_lds(                                                \
        (const __attribute__((address_space(1))) unsigned int*)(SRC),                \
        (__attribute__((address_space(3))) unsigned int*)(smem + (DSTOFF)), 16, 0, 0)

template<int MODE, int STORE>
__global__ __launch_bounds__(1024) void k_fused(
    const __bf16* __restrict__ Lb, const __bf16* __restrict__ Gf,
    const __bf16* __restrict__ Wt, const float* __restrict__ bias,
    __bf16* __restrict__ GB, float* __restrict__ u, float* __restrict__ h,
    const float* __restrict__ x_in, int xstride,
    const float* __restrict__ res_w, const float* __restrict__ res_b,
    const float* __restrict__ ln_g, const float* __restrict__ ln_b,
    float* __restrict__ x_out, __bf16* __restrict__ Gnext,
    __bf16* __restrict__ GhSelf,
    float* __restrict__ hg, __bf16* __restrict__ Hb,
    const __bf16* __restrict__ WihB, const __bf16* __restrict__ WhhB,
    const float* __restrict__ bih, const float* __restrict__ bhh,
    const float* __restrict__ inp, __bf16* __restrict__ xnextG, int tnext)
{
    __shared__ __align__(16) char smem[SMEMB];
    __bf16* sP   = (__bf16*)(smem + OFF_SP);
    __bf16* sGT  = (__bf16*)smem;               // MODE0 [256][72]
    __bf16* sT   = (__bf16*)smem;               // MODE1 [128][72]
    __bf16* sO   = (__bf16*)(smem + OFF_SO);    // MODE1 [64][136]
    float*  sScal= (float*)(smem + OFF_SCAL);
    float*  sSt  = (float*)(smem + OFF_SST);

    int tid = threadIdx.x;
    int wg = blockIdx.x;
    int b = wg & 15;                 // b%8 == XCD id
    int m0 = (wg >> 4) * 64;
    int wave = tid >> 6, lane = tid & 63;
    int lr = lane & 15, lk = lane >> 4;
    int wm = wave >> 3;              // m-half
    int wcg = wave & 7;              // c-group
    int cgbase = (wcg == 0) ? 0 : (wcg + 1) * 16;   // {0,32,48,...,128}
    int NC = (wcg == 0) ? 2 : 1;

    if (MODE == 0) {
        if (tid < 256) sScal[tid] = bias[tid];
    } else if (tid < 128) {
        sScal[tid] = bias[tid];
        sScal[128 + tid] = res_w[tid];
        sScal[256 + tid] = res_b[tid];
        sScal[384 + tid] = ln_g[tid];
        sScal[512 + tid] = ln_b[tid];
    }

    size_t srowOff = (size_t)b * GR * KP;
    int rIn = lane >> 3;
    int cswz = ((lane & 7) ^ rIn) * 8;   // pre-swizzled source col (elems)

    // staging: wave<10 -> chunks {2w, 2w+1}; wave>=10 -> chunk {wave+10}. 26 chunks total.
    int ch0 = (wave < 10) ? (2 * wave) : (wave + 10);
    int ch1 = 2 * wave + 1;
    const __bf16* src0 = (ch0 < 8)
        ? Lb + (size_t)(m0 + ch0 * 8 + rIn) * KP + cswz
        : Gf + srowOff + (size_t)((ch0 - 8) * 8 + rIn) * KP + cswz;
    const __bf16* src1 = (wave < 10)
        ? ((ch1 < 8) ? Lb + (size_t)(m0 + ch1 * 8 + rIn) * KP + cswz
                     : Gf + srowOff + (size_t)((ch1 - 8) * 8 + rIn) * KP + cswz)
        : (const __bf16*)nullptr;

#define STAGE(BUF, IT) {                                                \
    GL16(src0 + (IT) * 64, (BUF) * BUFSZ + ch0 * 1024);                 \
    if (wave < 10) GL16(src1 + (IT) * 64, (BUF) * BUFSZ + ch1 * 1024); }

    f32x4 acc[2][2];
#pragma unroll
    for (int i = 0; i < 2; i++)
#pragma unroll
        for (int j = 0; j < 2; j++) acc[i][j] = (f32x4){0.f, 0.f, 0.f, 0.f};

    STAGE(0, 0);
    STAGE(1, 1);
    int bc = 0;
    for (int it = 0; it < 16; ++it) {
        if (it == 15)       asm volatile("s_waitcnt vmcnt(0)" ::: "memory");
        else if (wave < 10) asm volatile("s_waitcnt vmcnt(2)" ::: "memory");
        else                asm volatile("s_waitcnt vmcnt(1)" ::: "memory");
        __builtin_amdgcn_s_barrier();
        __builtin_amdgcn_sched_barrier(0);
        const char* bp = smem + bc * BUFSZ;
#pragma unroll
        for (int ks = 0; ks < 2; ks++) {
            int kb = (ks * 64 + lk * 16) ^ ((lr & 7) << 4);
            bf16x8 af[2];
#pragma unroll
            for (int mf = 0; mf < 2; mf++) {
                int chA = wm * 4 + mf * 2 + (lr >> 3);
                af[mf] = *(const bf16x8*)(bp + chA * 1024 + (lr & 7) * 128 + kb);
            }
#pragma unroll
            for (int cf = 0; cf < 2; cf++) {
                if (cf < NC) {
                    int chB = 8 + (cgbase >> 3) + cf * 2 + (lr >> 3);
                    bf16x8 bfr = *(const bf16x8*)(bp + chB * 1024 + (lr & 7) * 128 + kb);
                    acc[0][cf] = MFMA16(af[0], bfr, acc[0][cf]);
                    acc[1][cf] = MFMA16(af[1], bfr, acc[1][cf]);
                }
            }
        }
        if (it < 14) { int bs = (it + 2) % 3; STAGE(bs, it + 2); }
        bc = (bc == 2) ? 0 : bc + 1;
    }
    __syncthreads();
#undef STAGE

    // P -> sP bf16
#pragma unroll
    for (int mf = 0; mf < 2; mf++)
#pragma unroll
        for (int cf = 0; cf < 2; cf++) {
            if (cf < NC) {
#pragma unroll
                for (int i = 0; i < 4; i++)
                    sP[(wm * 32 + mf * 16 + lk * 4 + i) * SPS + cgbase + cf * 16 + lr] =
                        (__bf16)acc[mf][cf][i];
            }
        }
    for (int q = tid; q < 64 * 16; q += 1024) sP[(q >> 4) * SPS + 144 + (q & 15)] = (__bf16)0.f;
    __syncthreads();

    // Stage 2 (waves 0-7)
    constexpr int NOF = (MODE == 0) ? 2 : 1;
    int o0 = wave * NOF * 16;
    f32x4 accs[4][NOF];
#pragma unroll
    for (int i = 0; i < 4; i++)
#pragma unroll
        for (int j = 0; j < NOF; j++) accs[i][j] = (f32x4){0.f, 0.f, 0.f, 0.f};
    if (wave < 8) {
#pragma unroll
        for (int kk2 = 0; kk2 < CP2; kk2 += 32) {
            bf16x8 pa[4];
#pragma unroll
            for (int mf2 = 0; mf2 < 4; mf2++)
                pa[mf2] = *(const bf16x8*)&sP[(mf2 * 16 + lr) * SPS + kk2 + lk * 8];
#pragma unroll
            for (int of = 0; of < NOF; of++) {
                bf16x8 wb = *(const bf16x8*)&Wt[(size_t)(o0 + of * 16 + lr) * CP2 + kk2 + lk * 8];
#pragma unroll
                for (int mf2 = 0; mf2 < 4; mf2++)
                    accs[mf2][of] = MFMA16(pa[mf2], wb, accs[mf2][of]);
            }
        }
    }

    if (MODE == 0) {
        if (tid < 8)
            *(bf16x8*)&GB[srowOff + m0 + tid * 8] = *(const bf16x8*)&Gf[srowOff + m0 + tid * 8];
        bool clean = (m0 + 64 <= 500);
        if (clean) {
            if (wave < 8) {
#pragma unroll
                for (int mf2 = 0; mf2 < 4; mf2++)
#pragma unroll
                    for (int of = 0; of < NOF; of++) {
                        int o = o0 + of * 16 + lr;
                        float bv = sScal[o];
#pragma unroll
                        for (int i = 0; i < 4; i++)
                            sGT[o * 72 + mf2 * 16 + lk * 4 + i] = (__bf16)sigmoidf_(accs[mf2][of][i] + bv);
                    }
            }
            __syncthreads();
            for (int q = tid; q < 128 * 16; q += 1024) {
                int j = q >> 4;
                int rnc = (q & 15) * 4;
                size_t gidx = srowOff + (size_t)(1 + j) * KP + 2 * m0 + rnc * 2;
                bf16x8 hv = *(const bf16x8*)&Gf[gidx];
                bf16x8 rv;
#pragma unroll
                for (int e = 0; e < 8; e++) {
                    int rnl = rnc + (e >> 1);
                    int hi = e & 1;
                    float g = (float)sGT[(hi * 128 + j) * 72 + rnl];
                    rv[e] = (__bf16)(g * (float)hv[e]);
                }
                *(bf16x8*)&GB[gidx] = rv;
            }
        } else if (wave < 8) {
#pragma unroll
            for (int mf2 = 0; mf2 < 4; mf2++)
#pragma unroll
                for (int of = 0; of < NOF; of++) {
                    int o = o0 + of * 16 + lr;
                    int j = o & 127, hi = o >> 7;
                    float bv = sScal[o];
#pragma unroll
                    for (int i = 0; i < 4; i++) {
                        int m = m0 + mf2 * 16 + lk * 4 + i;
                        if (m >= NN) continue;
                        float g = sigmoidf_(accs[mf2][of][i] + bv);
                        if (m < 500) {
                            size_t gi = srowOff + (size_t)(1 + j) * KP + 2 * m + hi;
                            GB[gi] = (__bf16)(g * (float)Gf[gi]);
                        } else {
                            u[((size_t)b * NN + 2 * (m - 500) + hi) * HH + j] = g;
                        }
                    }
                }
        }
    } else {
        int j = o0 + lr;   // NOF==1
        float hnv[4][4];
        float mu_[4][4], rs_[4][4];
        float xs_[4][4];
        if (wave < 8) {
            float s_[4][4], ss_[4][4];
#pragma unroll
            for (int a = 0; a < 4; a++)
#pragma unroll
                for (int i = 0; i < 4; i++) { s_[a][i] = 0.f; ss_[a][i] = 0.f; }
            float b2v = sScal[j], rwv = sScal[128 + j], rbv = sScal[256 + j];
#pragma unroll
            for (int mf2 = 0; mf2 < 4; mf2++) {
#pragma unroll
                for (int i = 0; i < 4; i++) {
                    int m = m0 + mf2 * 16 + lk * 4 + i;
                    int msafe = (m < NN) ? m : (NN - 1);
                    size_t ri = ((size_t)b * NN + msafe) * HH + j;
                    float cv = tanhf(accs[mf2][0][i] + b2v);
                    float uu = u[ri];
                    float hv = h[ri];
                    float hn = uu * hv + (1.f - uu) * cv;
                    if (m < NN) h[ri] = hn;
                    hnv[mf2][i] = hn;
                    float xv = (m < NN) ? x_in[(size_t)b * xstride + m] : 0.f;
                    float y = hn + xv * rwv + rbv;
                    accs[mf2][0][i] = y;
                    s_[mf2][i] += y; ss_[mf2][i] += y * y;
                }
            }
#pragma unroll
            for (int msk = 1; msk < 16; msk <<= 1)
#pragma unroll
                for (int a = 0; a < 4; a++)
#pragma unroll
                    for (int i = 0; i < 4; i++) {
                        s_[a][i] += __shfl_xor(s_[a][i], msk);
                        ss_[a][i] += __shfl_xor(ss_[a][i], msk);
                    }
            if (lr == 0) {
#pragma unroll
                for (int a = 0; a < 4; a++)
#pragma unroll
                    for (int i = 0; i < 4; i++) {
                        int ml = a * 16 + lk * 4 + i;
                        sSt[wave * 64 + ml] = s_[a][i];
                        sSt[512 + wave * 64 + ml] = ss_[a][i];
                    }
            }
        }
        __syncthreads();
        if (wave < 8) {
#pragma unroll
            for (int a = 0; a < 4; a++)
#pragma unroll
                for (int i = 0; i < 4; i++) {
                    int ml = a * 16 + lk * 4 + i;
                    float S = 0.f, SS = 0.f;
#pragma unroll
                    for (int w = 0; w < 8; w++) { S += sSt[w * 64 + ml]; SS += sSt[512 + w * 64 + ml]; }
                    float mu = S * (1.f / 128.f);
                    float var = SS * (1.f / 128.f) - mu * mu;
                    mu_[a][i] = mu;
                    rs_[a][i] = rsqrtf(var + 1e-5f);
                }
            float lg = sScal[384 + j], lb2 = sScal[512 + j];
#pragma unroll
            for (int mf2 = 0; mf2 < 4; mf2++)
#pragma unroll
                for (int i = 0; i < 4; i++) {
                    float ov = (accs[mf2][0][i] - mu_[mf2][i]) * rs_[mf2][i] * lg + lb2;
                    accs[mf2][0][i] = ov;
                    xs_[mf2][i] = ov;
                }
#pragma unroll
            for (int msk = 1; msk < 16; msk <<= 1)
#pragma unroll
                for (int a = 0; a < 4; a++)
#pragma unroll
                    for (int i = 0; i < 4; i++) xs_[a][i] += __shfl_xor(xs_[a][i], msk);
        }
        __syncthreads();
        if (wave < 8 && lr == 0) {
#pragma unroll
            for (int a = 0; a < 4; a++)
#pragma unroll
                for (int i = 0; i < 4; i++)
                    sSt[wave * 64 + a * 16 + lk * 4 + i] = xs_[a][i];
        }
        __syncthreads();
        if (wave == 0 && lr == 0) {
#pragma unroll
            for (int a = 0; a < 4; a++)
#pragma unroll
                for (int i = 0; i < 4; i++) {
                    int ml = a * 16 + lk * 4 + i;
                    int m = m0 + ml;
                    if (m < NN) {
                        float S = 0.f;
#pragma unroll
                        for (int w = 0; w < 8; w++) S += sSt[w * 64 + ml];
                        float xv = S * (1.f / 128.f);
                        if (x_out) x_out[(size_t)b * NN + m] = xv;
                        if (Gnext) Gnext[(size_t)b * GR * KP + m] = (__bf16)xv;
                    }
                }
        }
        if (wave < 8) {
#pragma unroll
            for (int mf2 = 0; mf2 < 4; mf2++)
#pragma unroll
                for (int i = 0; i < 4; i++)
                    sT[j * 72 + mf2 * 16 + lk * 4 + i] = (__bf16)hnv[mf2][i];
            if (STORE) {
#pragma unroll
                for (int mf2 = 0; mf2 < 4; mf2++)
#pragma unroll
                    for (int i = 0; i < 4; i++)
                        sO[(mf2 * 16 + lk * 4 + i) * 136 + j] = (__bf16)accs[mf2][0][i];
            }
        }
        __syncthreads();
        for (int q = tid; q < 128 * 8; q += 1024) {
            int jj = q >> 3, mc = (q & 7) * 8;
            if (m0 + mc < NN)
                *(bf16x8*)&GhSelf[srowOff + (size_t)(1 + jj) * KP + m0 + mc] =
                    *(const bf16x8*)&sT[jj * 72 + mc];
        }
        if (STORE) {
            // ---- fused GRU step (wave-local j-slice: r/z/n rows {j, 128+j, 256+j}) ----
            if (wave < 8) {
                float br  = bih[j] + bhh[j];
                float bz  = bih[128 + j] + bhh[128 + j];
                float bni = bih[256 + j], bnh = bhh[256 + j];
                const __bf16* wir = WihB + (size_t)j * HH;
                const __bf16* whr = WhhB + (size_t)j * HH;
                const __bf16* wiz = WihB + (size_t)(128 + j) * HH;
                const __bf16* whz = WhhB + (size_t)(128 + j) * HH;
                const __bf16* win = WihB + (size_t)(256 + j) * HH;
                const __bf16* whn = WhhB + (size_t)(256 + j) * HH;
#pragma unroll
                for (int mf = 0; mf < 4; mf++) {
                    f32x4 gr = (f32x4){0.f,0.f,0.f,0.f}, gz = gr, gni = gr, gnh = gr;
                    int rrow = m0 + mf * 16 + lr;
                    size_t hrow = (size_t)b * NN + ((rrow < NN) ? rrow : (NN - 1));
#pragma unroll
                    for (int kk = 0; kk < 128; kk += 32) {
                        bf16x8 xa = *(const bf16x8*)&sO[(mf * 16 + lr) * 136 + kk + lk * 8];
                        bf16x8 ha = *(const bf16x8*)&Hb[hrow * HH + kk + lk * 8];
                        gr  = MFMA16(xa, *(const bf16x8*)(wir + kk + lk * 8), gr);
                        gr  = MFMA16(ha, *(const bf16x8*)(whr + kk + lk * 8), gr);
                        gz  = MFMA16(xa, *(const bf16x8*)(wiz + kk + lk * 8), gz);
                        gz  = MFMA16(ha, *(const bf16x8*)(whz + kk + lk * 8), gz);
                        gni = MFMA16(xa, *(const bf16x8*)(win + kk + lk * 8), gni);
                        gnh = MFMA16(ha, *(const bf16x8*)(whn + kk + lk * 8), gnh);
                    }
#pragma unroll
                    for (int i = 0; i < 4; i++) {
                        int m = m0 + mf * 16 + lk * 4 + i;
                        if (m >= NN) continue;
                        size_t ri = ((size_t)b * NN + m) * HH + j;
                        float hv = hg[ri];
                        float rg = sigmoidf_(gr[i] + br);
                        float zg = sigmoidf_(gz[i] + bz);
                        float ng = tanhf(gni[i] + bni + rg * (gnh[i] + bnh));
                        float hp = (1.f - zg) * ng + zg * hv;
                        hg[ri] = hp;
                        Hb[ri] = (__bf16)hp;
                    }
                }
            }
            if (tid < 64 && tnext < TT) {
                int n = m0 + tid;
                if (n < NN)
                    xnextG[srowOff + n] = (__bf16)inp[(size_t)b * TT * NN + tnext * NN + n];
            }
        }
    }
}
#undef GL16

// ---------------- head: proj -> relu MLP -> out, MFMA ----------------
__global__ __launch_bounds__(256) void k_head_mfma(const __bf16* __restrict__ Hb,
                                                   const __bf16* __restrict__ projB,
                                                   const float* __restrict__ pb,
                                                   const __bf16* __restrict__ w1B,
                                                   const float* __restrict__ b1,
                                                   const __bf16* __restrict__ w2B,
                                                   const float* __restrict__ b2,
                                                   float* __restrict__ out) {
    __shared__ __align__(16) __bf16 sH1[64 * 136];
    __shared__ __align__(16) __bf16 sH2[64 * 264];
    int tid = threadIdx.x;
    int r0 = blockIdx.x * 64;
    int wv = tid >> 6, lane = tid & 63;
    int lr = lane & 15, lk = lane >> 4;
    int arow = r0 + wv * 16 + lr;

    f32x4 a1[8];
#pragma unroll
    for (int i = 0; i < 8; i++) a1[i] = (f32x4){0.f, 0.f, 0.f, 0.f};
#pragma unroll
    for (int kk = 0; kk < 128; kk += 32) {
        bf16x8 xa = *(const bf16x8*)&Hb[(size_t)arow * HH + kk + lk * 8];
#pragma unroll
        for (int f = 0; f < 8; f++) {
            bf16x8 wb = *(const bf16x8*)&projB[(size_t)(f * 16 + lr) * HH + kk + lk * 8];
            a1[f] = MFMA16(xa, wb, a1[f]);
        }
    }
#pragma unroll
    for (int f = 0; f < 8; f++) {
        int j = f * 16 + lr;
        float bv = pb[j];
#pragma unroll
        for (int i = 0; i < 4; i++)
            sH1[(wv * 16 + lk * 4 + i) * 136 + j] = (__bf16)(a1[f][i] + bv);
    }
    __syncthreads();

    f32x4 a2[16];
#pragma unroll
    for (int i = 0; i < 16; i++) a2[i] = (f32x4){0.f, 0.f, 0.f, 0.f};
#pragma unroll
    for (int kk = 0; kk < 128; kk += 32) {
        bf16x8 pa = *(const bf16x8*)&sH1[(wv * 16 + lr) * 136 + kk + lk * 8];
#pragma unroll
        for (int f = 0; f < 16; f++) {
            bf16x8 wb = *(const bf16x8*)&w1B[(size_t)(f * 16 + lr) * HH + kk + lk * 8];
            a2[f] = MFMA16(pa, wb, a2[f]);
        }
    }
    __syncthreads();
#pragma unroll
    for (int f = 0; f < 16; f++) {
        int o = f * 16 + lr;
        float bv = b1[o];
#pragma unroll
        for (int i = 0; i < 4; i++)
            sH2[(wv * 16 + lk * 4 + i) * 264 + o] = (__bf16)fmaxf(a2[f][i] + bv, 0.f);
    }
    __syncthreads();

    f32x4 a3[8];
#pragma unroll
    for (int i = 0; i < 8; i++) a3[i] = (f32x4){0.f, 0.f, 0.f, 0.f};
#pragma unroll
    for (int kk = 0; kk < 256; kk += 32) {
        bf16x8 pa = *(const bf16x8*)&sH2[(wv * 16 + lr) * 264 + kk + lk * 8];
#pragma unroll
        for (int f = 0; f < 8; f++) {
            bf16x8 wb = *(const bf16x8*)&w2B[(size_t)(f * 16 + lr) * 256 + kk + lk * 8];
            a3[f] = MFMA16(pa, wb, a3[f]);
        }
    }
#pragma unroll
    for (int f = 0; f < 8; f++) {
        int j = f * 16 + lr;
        float bv = b2[j];
#pragma unroll
        for (int i = 0; i < 4; i++)
            out[(size_t)(r0 + wv * 16 + lk * 4 + i) * HH + j] = a3[f][i] + bv;
    }
}

extern "C" void kernel_launch(void* const* d_in, const int* in_sizes, int n_in,
                              void* d_out, int out_size, void* d_ws, size_t ws_size,
                              hipStream_t stream) {
    const float* inp    = (const float*)d_in[0];
    const float* adj    = (const float*)d_in[1];
    const float* gc1_w  = (const float*)d_in[2];
    const float* gc1_b  = (const float*)d_in[3];
    const float* gc2_w  = (const float*)d_in[4];
    const float* gc2_b  = (const float*)d_in[5];
    const float* ln_g   = (const float*)d_in[6];
    const float* ln_b   = (const float*)d_in[7];
    const float* res_w  = (const float*)d_in[8];
    const float* res_b  = (const float*)d_in[9];
    const float* wih    = (const float*)d_in[10];
    const float* whh    = (const float*)d_in[11];
    const float* bih    = (const float*)d_in[12];
    const float* bhh    = (const float*)d_in[13];
    const float* proj_w = (const float*)d_in[14];
    const float* proj_b = (const float*)d_in[15];
    const float* ow1    = (const float*)d_in[16];
    const float* ob1    = (const float*)d_in[17];
    const float* ow2    = (const float*)d_in[18];
    const float* ob2    = (const float*)d_in[19];
    float* out = (float*)d_out;

    char* ws = (char*)d_ws;
    size_t off = 0;
    __bf16* Lb     = (__bf16*)(ws + off); off += (size_t)KP * KP * 2;          // 2 MB
    __bf16* Gfull0 = (__bf16*)(ws + off); off += (size_t)BB * GR * KP * 2;     // 5 MB
    __bf16* Gfull1 = (__bf16*)(ws + off); off += (size_t)BB * GR * KP * 2;
    __bf16* GfullB = (__bf16*)(ws + off); off += (size_t)BB * GR * KP * 2;
    size_t zgrp1 = off;
    float* h0   = (float*)(ws + off);  off += (size_t)NROW * HH * 4;
    float* h1   = (float*)(ws + off);  off += (size_t)NROW * HH * 4;
    float* hg   = (float*)(ws + off);  off += (size_t)NROW * HH * 4;
    __bf16* Hb  = (__bf16*)(ws + off); off += (size_t)NROW * HH * 2;
    float* u    = (float*)(ws + off);  off += (size_t)NROW * HH * 4;
    float* xB   = (float*)(ws + off);  off += NROW * 4;
    __bf16* W1t = (__bf16*)(ws + off); off += (size_t)2 * 256 * CP2 * 2;
    __bf16* W2t = (__bf16*)(ws + off); off += (size_t)2 * 128 * CP2 * 2;
    __bf16* WihB= (__bf16*)(ws + off); off += 49152 * 2;
    __bf16* WhhB= (__bf16*)(ws + off); off += 49152 * 2;
    __bf16* projB=(__bf16*)(ws + off); off += 16384 * 2;
    __bf16* w1B = (__bf16*)(ws + off); off += 32768 * 2;
    __bf16* w2B = (__bf16*)(ws + off); off += 32768 * 2;
    float* a_sm = u;   // overlay: softmax scratch only used before u's first write

    hipMemsetAsync(Lb, 0, zgrp1, stream);                     // Lb + Gfull0/1/B
    hipMemsetAsync(h0, 0, (size_t)NROW * HH * 8, stream);     // h0, h1
    hipMemsetAsync(hg, 0, (size_t)NROW * HH * 6, stream);     // hg, Hb

    k_softmax<<<NN, 256, 0, stream>>>(adj, a_sm);
    k_build_Lt<<<dim3(16, 16), 256, 0, stream>>>(a_sm, Lb);
    k_prep<<<1184, 256, 0, stream>>>(wih, whh, proj_w, ow1, ow2, gc1_w, gc2_w,
                                     WihB, WhhB, projB, w1B, w2B, W1t, W2t);
    k_prep_x<<<64, 256, 0, stream>>>(inp, Gfull0);

    for (int t = 0; t < TT; t++) {
        const float* xs0 = inp + (size_t)t * NN;
        // layer 0
        k_fused<0, 0><<<256, 1024, 0, stream>>>(Lb, Gfull0, W1t, gc1_b, GfullB, u,
            nullptr, nullptr, 0, nullptr, nullptr, nullptr, nullptr,
            nullptr, nullptr, nullptr,
            nullptr, nullptr, nullptr, nullptr, nullptr, nullptr, nullptr, nullptr, 0);
        k_fused<1, 0><<<256, 1024, 0, stream>>>(Lb, GfullB, W2t, gc2_b, nullptr, u, h0,
            xs0, TT * NN, res_w, res_b, ln_g, ln_b,
            xB, Gfull1, Gfull0,
            nullptr, nullptr, nullptr, nullptr, nullptr, nullptr, nullptr, nullptr, 0);
        // layer 1
        k_fused<0, 0><<<256, 1024, 0, stream>>>(Lb, Gfull1, W1t + 256 * CP2, gc1_b + 256, GfullB, u,
            nullptr, nullptr, 0, nullptr, nullptr, nullptr, nullptr,
            nullptr, nullptr, nullptr,
            nullptr, nullptr, nullptr, nullptr, nullptr, nullptr, nullptr, nullptr, 0);
        k_fused<1, 1><<<256, 1024, 0, stream>>>(Lb, GfullB, W2t + 128 * CP2, gc2_b + 128, nullptr, u, h1,
            xB, NN, res_w, res_b, ln_g + 128, ln_b + 128,
            nullptr, nullptr, Gfull1,
            hg, Hb, WihB, WhhB, bih, bhh, inp, Gfull0, t + 1);
    }
    k_head_mfma<<<250, 256, 0, stream>>>(Hb, projB, proj_b, w1B, ob1, w2B, ob2, out);
}